// Round 2
// baseline (3486.578 us; speedup 1.0000x reference)
//
#include <hip/hip_runtime.h>
#include <cmath>

#define LSEQ 32
#define HID  512
#define DIN  1536
#define CCH  64
#define NROW 2048          // E*S
#define NL   65536         // NROW*LSEQ
#define WC_FLOATS (7*512*512)

// ---------------- pack conv weights: Wc[dl+3][ci][c], c in [0,512) ----------------
__global__ void pack_wc_kernel(const float* __restrict__ w1, const float* __restrict__ w3,
                               const float* __restrict__ w5, const float* __restrict__ w7,
                               float* __restrict__ Wc) {
  int idx = blockIdx.x * 256 + threadIdx.x;
  if (idx >= WC_FLOATS) return;
  int c   = idx & 511;
  int ci  = (idx >> 9) & 511;
  int dli = idx >> 18;           // 0..6
  int dl  = dli - 3;
  int g   = c >> 7, cg = c & 127;
  int K   = 2 * g + 1;
  int kk  = dl + g;
  float v = 0.f;
  if (kk >= 0 && kk < K) {
    const float* w = (g == 0) ? w1 : (g == 1) ? w3 : (g == 2) ? w5 : w7;
    v = w[(cg * 512 + ci) * K + kk];   // (Cout_g, Cin, K) row-major
  }
  Wc[idx] = v;
}

// ---------------- step 0: h1 = tanh(xw + bh) ----------------
__global__ void step0_kernel(const float* __restrict__ xw, const float* __restrict__ bh,
                             float* __restrict__ hs, int total) {
  int idx = blockIdx.x * 256 + threadIdx.x;   // < R*512
  if (idx >= total) return;
  int n = idx >> 9, h = idx & 511;
  hs[(long)n * (LSEQ * HID) + h] = tanhf(xw[idx] + bh[h]);
}

// ---------------- generic fp32 GEMM, 64x64 tile, 4x4 micro ----------------
// C[m,n] = epilogue( sum_k A[m,k]*B[k,n] )
// epilogue: addv ? tanh(acc + addv[m,n] + bias[n]) : acc + bias[n]
__global__ __launch_bounds__(256) void gemm64_kernel(
    const float* __restrict__ A, int lda,
    const float* __restrict__ B, int ldb,
    float* __restrict__ C, int ldc, int K,
    const float* __restrict__ addv, int ldadd,
    const float* __restrict__ bias)
{
  __shared__ float As[16][68];
  __shared__ float Bs[16][64];
  const int tid = threadIdx.x;
  const int m0 = blockIdx.x * 64;
  const int n0 = blockIdx.y * 64;
  const int ty = tid >> 4, tx = tid & 15;
  const int arow = tid >> 2;           // 0..63
  const int akq  = (tid & 3) * 4;      // 0,4,8,12
  const int brow = tid >> 4;           // 0..15
  const int bcol = (tid & 15) * 4;     // 0..60
  const float* Ap = A + (long)(m0 + arow) * lda + akq;
  const float* Bp = B + (long)brow * ldb + n0 + bcol;

  float acc[4][4] = {};
  for (int k0 = 0; k0 < K; k0 += 16) {
    float4 av = *(const float4*)(Ap + k0);
    float4 bv = *(const float4*)(Bp + (long)k0 * ldb);
    __syncthreads();
    As[akq + 0][arow] = av.x;
    As[akq + 1][arow] = av.y;
    As[akq + 2][arow] = av.z;
    As[akq + 3][arow] = av.w;
    *(float4*)&Bs[brow][bcol] = bv;
    __syncthreads();
#pragma unroll
    for (int k = 0; k < 16; ++k) {
      float4 a4 = *(const float4*)&As[k][ty * 4];
      float4 b4 = *(const float4*)&Bs[k][tx * 4];
      const float a[4] = {a4.x, a4.y, a4.z, a4.w};
      const float b[4] = {b4.x, b4.y, b4.z, b4.w};
#pragma unroll
      for (int i = 0; i < 4; ++i)
#pragma unroll
        for (int j = 0; j < 4; ++j)
          acc[i][j] = fmaf(a[i], b[j], acc[i][j]);
    }
  }

  const int cm = m0 + ty * 4;
  const int cn = n0 + tx * 4;
  float4 bv4 = *(const float4*)&bias[cn];
  const float bb[4] = {bv4.x, bv4.y, bv4.z, bv4.w};
#pragma unroll
  for (int i = 0; i < 4; ++i) {
    float v[4];
    if (addv) {
      const float* ap = addv + (long)(cm + i) * ldadd + cn;
#pragma unroll
      for (int j = 0; j < 4; ++j) v[j] = tanhf(acc[i][j] + ap[j] + bb[j]);
    } else {
#pragma unroll
      for (int j = 0; j < 4; ++j) v[j] = acc[i][j] + bb[j];
    }
    float4 o; o.x = v[0]; o.y = v[1]; o.z = v[2]; o.w = v[3];
    *(float4*)(C + (long)(cm + i) * ldc + cn) = o;
  }
}

// ---------------- fused 4-kernel conv1d (reflect) + bias + PReLU ----------------
// y[r, c] = prelu( sum_{dl=-g..g} sum_ci hs[reflect(r,dl), ci] * Wc[dl+3][ci][c] + b_g[c&127] )
// block: 128 rows x 128 cols (one group g = blockIdx.y); row indices chunk-local
__global__ __launch_bounds__(256) void conv_gemm_kernel(
    const float* __restrict__ hs,   // Rl x 512 (chunk)
    const float* __restrict__ Wc,   // 7 x 512 x 512
    const float* __restrict__ b1, const float* __restrict__ b3,
    const float* __restrict__ b5, const float* __restrict__ b7,
    const float* __restrict__ prelu_a,
    float* __restrict__ y)          // Rl x 512 (chunk)
{
  __shared__ float As[16][132];
  __shared__ float Bs[16][128];
  const int tid = threadIdx.x;
  const int r0 = blockIdx.x * 128;
  const int g  = blockIdx.y;          // 0..3
  const int n0 = g * 128;
  const int ty = tid >> 4, tx = tid & 15;
  const int arow = tid >> 1;           // 0..127
  const int akq  = (tid & 1) * 8;      // 0 or 8
  const int brow = tid >> 4;           // 0..15
  const int bcol = (tid & 15) * 4;     // 0..60

  float acc[8][8] = {};

  const int rr    = r0 + arow;
  const int rbase = rr & ~31;
  const int l     = rr & 31;

  for (int dl = -g; dl <= g; ++dl) {
    int lp = l + dl;
    lp = (lp < 0) ? -lp : ((lp > 31) ? 62 - lp : lp);   // reflect padding
    const float* Ap = hs + (long)(rbase + lp) * 512 + akq;
    const float* Bp = Wc + (long)(dl + 3) * (512 * 512) + n0 + bcol;
    for (int k0 = 0; k0 < 512; k0 += 16) {
      float4 av0 = *(const float4*)(Ap + k0);
      float4 av1 = *(const float4*)(Ap + k0 + 4);
      float4 bv0 = *(const float4*)(Bp + (long)(k0 + brow) * 512);
      float4 bv1 = *(const float4*)(Bp + (long)(k0 + brow) * 512 + 64);
      __syncthreads();
      As[akq + 0][arow] = av0.x;
      As[akq + 1][arow] = av0.y;
      As[akq + 2][arow] = av0.z;
      As[akq + 3][arow] = av0.w;
      As[akq + 4][arow] = av1.x;
      As[akq + 5][arow] = av1.y;
      As[akq + 6][arow] = av1.z;
      As[akq + 7][arow] = av1.w;
      *(float4*)&Bs[brow][bcol]      = bv0;
      *(float4*)&Bs[brow][bcol + 64] = bv1;
      __syncthreads();
#pragma unroll
      for (int k = 0; k < 16; ++k) {
        float4 a0 = *(const float4*)&As[k][ty * 4];
        float4 a1 = *(const float4*)&As[k][64 + ty * 4];
        float4 q0 = *(const float4*)&Bs[k][tx * 4];
        float4 q1 = *(const float4*)&Bs[k][64 + tx * 4];
        const float a[8] = {a0.x, a0.y, a0.z, a0.w, a1.x, a1.y, a1.z, a1.w};
        const float b[8] = {q0.x, q0.y, q0.z, q0.w, q1.x, q1.y, q1.z, q1.w};
#pragma unroll
        for (int i = 0; i < 8; ++i)
#pragma unroll
          for (int j = 0; j < 8; ++j)
            acc[i][j] = fmaf(a[i], b[j], acc[i][j]);
      }
    }
  }

  const float pa = *prelu_a;
  const float* bg = (g == 0) ? b1 : (g == 1) ? b3 : (g == 2) ? b5 : b7;
#pragma unroll
  for (int ib = 0; ib < 2; ++ib)
#pragma unroll
    for (int i = 0; i < 4; ++i) {
      const int r = r0 + ib * 64 + ty * 4 + i;
#pragma unroll
      for (int jb = 0; jb < 2; ++jb) {
        const int c = n0 + jb * 64 + tx * 4;
        float v[4];
#pragma unroll
        for (int j = 0; j < 4; ++j) {
          float t = acc[ib * 4 + i][jb * 4 + j] + bg[(c + j) & 127];
          v[j] = (t >= 0.f) ? t : pa * t;
        }
        float4 o; o.x = v[0]; o.y = v[1]; o.z = v[2]; o.w = v[3];
        *(float4*)(y + (long)r * 512 + c) = o;
      }
    }
}

// ---------------- end-token mask, in place on d_out ----------------
__global__ void mask_kernel(float* __restrict__ out) {
  const int row  = blockIdx.x;     // 0..2047 (e,s)
  const int lane = threadIdx.x;    // 0..63 = channel
  float* base = out + (long)row * (LSEQ * CCH);
  int ended = 0;
  for (int l = 0; l < LSEQ; ++l) {
    float v = base[l * CCH + lane];
    float mv = v; int mi = lane;
#pragma unroll
    for (int off = 32; off > 0; off >>= 1) {
      float ov = __shfl_xor(mv, off);
      int   oi = __shfl_xor(mi, off);
      if (ov > mv || (ov == mv && oi < mi)) { mv = ov; mi = oi; }  // first-max tie-break
    }
    if (ended) base[l * CCH + lane] = 0.f;
    ended |= (mi == 0);
  }
}

extern "C" void kernel_launch(void* const* d_in, const int* in_sizes, int n_in,
                              void* d_out, int out_size, void* d_ws, size_t ws_size,
                              hipStream_t stream) {
  const float* x    = (const float*)d_in[0];   // (2048, 1536)
  const float* Wx   = (const float*)d_in[1];   // (1536, 512)
  const float* bx   = (const float*)d_in[2];   // (512,)
  const float* Wh   = (const float*)d_in[3];   // (512, 512)
  const float* bh   = (const float*)d_in[4];   // (512,)
  const float* pa   = (const float*)d_in[5];   // scalar
  const float* Wout = (const float*)d_in[6];   // (512, 64)
  const float* bout = (const float*)d_in[7];   // (64,)
  const float* cw1  = (const float*)d_in[8];
  const float* cb1  = (const float*)d_in[9];
  const float* cw3  = (const float*)d_in[10];
  const float* cb3  = (const float*)d_in[11];
  const float* cw5  = (const float*)d_in[12];
  const float* cb5  = (const float*)d_in[13];
  const float* cw7  = (const float*)d_in[14];
  const float* cb7  = (const float*)d_in[15];
  float* out = (float*)d_out;

  // ---- choose row-chunking so the workspace fits ws_size ----
  // per-chunk floats: Wc + xw(R*512) + hs(R*32*512) + y(R*32*512)
  int nc = 1;
  while (nc < 16) {
    size_t R = NROW / nc;
    size_t need = 4ull * ((size_t)WC_FLOATS + R * 512 + 2ull * R * LSEQ * HID);
    if (need <= ws_size) break;
    nc *= 2;
  }
  const int R  = NROW / nc;      // rows (e,s pairs) per chunk
  const int RL = R * LSEQ;       // l-rows per chunk

  float* ws = (float*)d_ws;
  float* Wc = ws;                                 // 7*512*512
  float* xw = Wc + (size_t)WC_FLOATS;             // R*512
  float* hs = xw + (size_t)R * HID;               // R*32*512
  float* y  = hs + (size_t)R * LSEQ * HID;        // R*32*512

  // 1) pack conv weights (once)
  pack_wc_kernel<<<(WC_FLOATS + 255) / 256, 256, 0, stream>>>(cw1, cw3, cw5, cw7, Wc);

  for (int c = 0; c < nc; ++c) {
    const size_t row0 = (size_t)c * R;

    // 2) xw = x_chunk @ Wx + bx
    gemm64_kernel<<<dim3(R / 64, HID / 64), 256, 0, stream>>>(
        x + row0 * DIN, DIN, Wx, HID, xw, HID, DIN, nullptr, 0, bx);

    // 3) h_1 = tanh(xw + bh)  (h0 = 0)
    step0_kernel<<<(R * HID + 255) / 256, 256, 0, stream>>>(xw, bh, hs, R * HID);

    // 4) 31 recurrent steps: hs[:,t,:] = tanh(xw + hs[:,t-1,:] @ Wh + bh)
    for (int t = 1; t < LSEQ; ++t) {
      gemm64_kernel<<<dim3(R / 64, HID / 64), 256, 0, stream>>>(
          hs + (size_t)(t - 1) * HID, LSEQ * HID, Wh, HID,
          hs + (size_t)t * HID, LSEQ * HID, HID,
          xw, HID, bh);
    }

    // 5) fused Ted_Conv1d (+bias +PReLU) -> y (RL x 512)
    conv_gemm_kernel<<<dim3(RL / 128, 4), 256, 0, stream>>>(
        hs, Wc, cb1, cb3, cb5, cb7, pa, y);

    // 6) comm_pred = y @ Wout + bout -> d_out chunk (RL x 64)
    gemm64_kernel<<<dim3(RL / 64, CCH / 64), 256, 0, stream>>>(
        y, HID, Wout, CCH, out + row0 * LSEQ * CCH, CCH, HID, nullptr, 0, bout);
  }

  // 7) end-token mask in place
  mask_kernel<<<NROW, 64, 0, stream>>>(out);
}

// Round 3
// 1001.525 us; speedup vs baseline: 3.4813x; 3.4813x over previous
//
#include <hip/hip_runtime.h>
#include <cmath>

#define LSEQ 32
#define HID  512
#define DIN  1536
#define CCH  64
#define NROW 2048          // E*S
#define NL   65536         // NROW*LSEQ

typedef _Float16 f16;
typedef _Float16 f16x8 __attribute__((ext_vector_type(8)));
typedef float    f32x4 __attribute__((ext_vector_type(4)));

__device__ __forceinline__ float fast_tanh(float x) {
  float e = __expf(2.0f * x);
  return 1.0f - 2.0f * __builtin_amdgcn_rcpf(e + 1.0f);
}

// ---- LDS tile helpers: rows of 64B (32 f16), XOR-swizzled at 8B granularity ----
// swizzle: byte ^= (row&7)<<3  -> conflict-free b64 reads for 16-lane row groups
__device__ __forceinline__ void lds_st16(char* base, int r, int o, int4 v) {
  int b0 = (r << 6) + o;
  int sw = (r & 7) << 3;
  union { int4 i; unsigned long long u[2]; } U; U.i = v;
  *(unsigned long long*)(base + ((b0    ) ^ sw)) = U.u[0];
  *(unsigned long long*)(base + ((b0 + 8) ^ sw)) = U.u[1];
}
__device__ __forceinline__ f16x8 lds_ld_frag(const char* base, int r, int q) {
  int b0 = (r << 6) + (q << 4);
  int sw = (r & 7) << 3;
  union { unsigned long long u[2]; f16x8 v; } U;
  U.u[0] = *(const unsigned long long*)(base + ((b0    ) ^ sw));
  U.u[1] = *(const unsigned long long*)(base + ((b0 + 8) ^ sw));
  return U.v;
}

// ---------------- pack conv weights transposed: Wc_t[dl+3][c][k] f16 ----------------
__global__ void pack_wc_kernel(const float* __restrict__ w1, const float* __restrict__ w3,
                               const float* __restrict__ w5, const float* __restrict__ w7,
                               f16* __restrict__ Wc_t) {
  int idx = blockIdx.x * 256 + threadIdx.x;
  if (idx >= 7 * 512 * 512) return;
  int k   = idx & 511;          // contraction (input channel)
  int c   = (idx >> 9) & 511;   // output channel
  int dli = idx >> 18;          // 0..6
  int dl  = dli - 3;
  int g   = c >> 7, cg = c & 127;
  int K   = 2 * g + 1;
  int kk  = dl + g;
  float v = 0.f;
  if (kk >= 0 && kk < K) {
    const float* w = (g == 0) ? w1 : (g == 1) ? w3 : (g == 2) ? w5 : w7;
    v = w[(cg * 512 + k) * K + kk];   // (Cout_g, Cin, K) row-major
  }
  Wc_t[idx] = (f16)v;
}

// ---------------- pack Wh^T and Wout^T as f16 ----------------
__global__ void pack_misc_kernel(const float* __restrict__ Wh, const float* __restrict__ Wout,
                                 f16* __restrict__ Wh_t, f16* __restrict__ Wout_t) {
  int idx = blockIdx.x * 256 + threadIdx.x;
  if (idx < 512 * 512) {
    int n = idx >> 9, k = idx & 511;
    Wh_t[idx] = (f16)Wh[k * 512 + n];           // Wh_t[n][k]
  } else {
    int j = idx - 512 * 512;
    if (j < 64 * 512) {
      int c = j >> 9, k = j & 511;
      Wout_t[j] = (f16)Wout[k * 64 + c];        // Wout_t[c][k]
    }
  }
}

// ---------------- fp32 GEMM for xw = x @ Wx + bx (kept from round 2) ----------------
__global__ __launch_bounds__(256) void gemm64_kernel(
    const float* __restrict__ A, int lda,
    const float* __restrict__ B, int ldb,
    float* __restrict__ C, int ldc, int K,
    const float* __restrict__ addv, int ldadd,
    const float* __restrict__ bias)
{
  __shared__ float As[16][68];
  __shared__ float Bs[16][64];
  const int tid = threadIdx.x;
  const int m0 = blockIdx.x * 64;
  const int n0 = blockIdx.y * 64;
  const int ty = tid >> 4, tx = tid & 15;
  const int arow = tid >> 2;
  const int akq  = (tid & 3) * 4;
  const int brow = tid >> 4;
  const int bcol = (tid & 15) * 4;
  const float* Ap = A + (long)(m0 + arow) * lda + akq;
  const float* Bp = B + (long)brow * ldb + n0 + bcol;

  float acc[4][4] = {};
  for (int k0 = 0; k0 < K; k0 += 16) {
    float4 av = *(const float4*)(Ap + k0);
    float4 bv = *(const float4*)(Bp + (long)k0 * ldb);
    __syncthreads();
    As[akq + 0][arow] = av.x;
    As[akq + 1][arow] = av.y;
    As[akq + 2][arow] = av.z;
    As[akq + 3][arow] = av.w;
    *(float4*)&Bs[brow][bcol] = bv;
    __syncthreads();
#pragma unroll
    for (int k = 0; k < 16; ++k) {
      float4 a4 = *(const float4*)&As[k][ty * 4];
      float4 b4 = *(const float4*)&Bs[k][tx * 4];
      const float a[4] = {a4.x, a4.y, a4.z, a4.w};
      const float b[4] = {b4.x, b4.y, b4.z, b4.w};
#pragma unroll
      for (int i = 0; i < 4; ++i)
#pragma unroll
        for (int j = 0; j < 4; ++j)
          acc[i][j] = fmaf(a[i], b[j], acc[i][j]);
    }
  }
  const int cm = m0 + ty * 4;
  const int cn = n0 + tx * 4;
  float4 bv4 = *(const float4*)&bias[cn];
  const float bb[4] = {bv4.x, bv4.y, bv4.z, bv4.w};
#pragma unroll
  for (int i = 0; i < 4; ++i) {
    float v[4];
#pragma unroll
    for (int j = 0; j < 4; ++j) v[j] = acc[i][j] + bb[j];
    float4 o; o.x = v[0]; o.y = v[1]; o.z = v[2]; o.w = v[3];
    *(float4*)(C + (long)(cm + i) * ldc + cn) = o;
  }
}

// ---------------- step 0: h1 = tanh(xw + bh), write hi/lo f16 ----------------
__global__ void step0_kernel(const float* __restrict__ xw, const float* __restrict__ bh,
                             f16* __restrict__ hs_hi, f16* __restrict__ hlo0) {
  int idx = blockIdx.x * 256 + threadIdx.x;   // < 2048*512
  int n = idx >> 9, h = idx & 511;
  float v = fast_tanh(xw[idx] + bh[h]);
  f16 hi = (f16)v;
  hs_hi[(size_t)n * (LSEQ * HID) + h] = hi;   // t = 0 slot
  hlo0[idx] = (f16)(v - (float)hi);
}

// ---------------- RNN step t: h_t = tanh(xw + h_{t-1} @ Wh + bh), 2-product f16 MFMA ----------------
__global__ __launch_bounds__(256) void rnn_step_kernel(
    f16* __restrict__ hs_hi, const f16* __restrict__ hlo_prev,
    f16* __restrict__ hlo_cur, const f16* __restrict__ Wh_t,
    const float* __restrict__ xw, const float* __restrict__ bh, int t)
{
  __shared__ __align__(16) char lds[24576];
  char* Ahi = lds;            // 128 rows x 64B
  char* Alo = lds + 8192;     // 128 rows x 64B
  char* Bl  = lds + 16384;    // 128 rows x 64B
  const int tid = threadIdx.x;
  const int r0 = blockIdx.x * 128;       // batch rows (n)
  const int c0 = blockIdx.y * 128;       // hidden cols
  const int sr = tid >> 1, hf = (tid & 1) * 32;
  const int wave = tid >> 6, lane = tid & 63;
  const int wr = (wave >> 1) * 64, wc = (wave & 1) * 64;
  const int q = lane >> 4, ln = lane & 15;

  f32x4 acc[4][4] = {};
  const f16* srcAhi = hs_hi + ((size_t)(r0 + sr) * LSEQ + (t - 1)) * HID;
  const f16* srcAlo = hlo_prev + (size_t)(r0 + sr) * HID;
  const f16* srcB   = Wh_t + (size_t)(c0 + sr) * HID;

  for (int k0 = 0; k0 < HID; k0 += 32) {
    __syncthreads();
    {
      const char* pa = (const char*)(srcAhi + k0) + hf;
      const char* pl = (const char*)(srcAlo + k0) + hf;
      const char* pb = (const char*)(srcB   + k0) + hf;
      lds_st16(Ahi, sr, hf + 0,  *(const int4*)(pa));
      lds_st16(Ahi, sr, hf + 16, *(const int4*)(pa + 16));
      lds_st16(Alo, sr, hf + 0,  *(const int4*)(pl));
      lds_st16(Alo, sr, hf + 16, *(const int4*)(pl + 16));
      lds_st16(Bl,  sr, hf + 0,  *(const int4*)(pb));
      lds_st16(Bl,  sr, hf + 16, *(const int4*)(pb + 16));
    }
    __syncthreads();
    f16x8 a0[4], a1[4], bf[4];
#pragma unroll
    for (int m = 0; m < 4; ++m) {
      a0[m] = lds_ld_frag(Ahi, wr + m * 16 + ln, q);
      a1[m] = lds_ld_frag(Alo, wr + m * 16 + ln, q);
    }
#pragma unroll
    for (int n = 0; n < 4; ++n) bf[n] = lds_ld_frag(Bl, wc + n * 16 + ln, q);
#pragma unroll
    for (int m = 0; m < 4; ++m)
#pragma unroll
      for (int n = 0; n < 4; ++n) {
        acc[m][n] = __builtin_amdgcn_mfma_f32_16x16x32_f16(a0[m], bf[n], acc[m][n], 0, 0, 0);
        acc[m][n] = __builtin_amdgcn_mfma_f32_16x16x32_f16(a1[m], bf[n], acc[m][n], 0, 0, 0);
      }
  }
#pragma unroll
  for (int m = 0; m < 4; ++m)
#pragma unroll
    for (int i = 0; i < 4; ++i) {
      const int R = r0 + wr + m * 16 + q * 4 + i;
#pragma unroll
      for (int n = 0; n < 4; ++n) {
        const int C = c0 + wc + n * 16 + ln;
        float v = fast_tanh(acc[m][n][i] + xw[(size_t)R * HID + C] + bh[C]);
        f16 hi = (f16)v;
        hs_hi[((size_t)R * LSEQ + t) * HID + C] = hi;
        hlo_cur[(size_t)R * HID + C] = (f16)(v - (float)hi);
      }
    }
}

// ---------------- fused Ted_Conv1d via MFMA: A staged once/k-step, taps remap LDS rows ----------------
__global__ __launch_bounds__(256) void conv_mfma_kernel(
    const f16* __restrict__ hs_hi, const f16* __restrict__ Wc_t,
    const float* __restrict__ b1, const float* __restrict__ b3,
    const float* __restrict__ b5, const float* __restrict__ b7,
    const float* __restrict__ prelu_a, f16* __restrict__ y)
{
  __shared__ __align__(16) char lds[16384];
  char* Al = lds;             // 128 x 64B
  char* Bl = lds + 8192;      // 128 x 64B
  const int tid = threadIdx.x;
  const int r0 = blockIdx.x * 128;      // (n,t) rows
  const int g  = blockIdx.y;            // group 0..3
  const int sr = tid >> 1, hf = (tid & 1) * 32;
  const int wave = tid >> 6, lane = tid & 63;
  const int wr = (wave >> 1) * 64, wc = (wave & 1) * 64;
  const int q = lane >> 4, ln = lane & 15;

  f32x4 acc[4][4] = {};
  const f16* srcA = hs_hi + (size_t)(r0 + sr) * HID;
  const int taps = 2 * g + 1;

  for (int k0 = 0; k0 < HID; k0 += 32) {
    __syncthreads();
    {
      const char* pa = (const char*)(srcA + k0) + hf;
      lds_st16(Al, sr, hf + 0,  *(const int4*)(pa));
      lds_st16(Al, sr, hf + 16, *(const int4*)(pa + 16));
    }
    for (int tp = 0; tp < taps; ++tp) {
      const int dl = tp - g;
      if (tp) __syncthreads();
      {
        const f16* srcB = Wc_t + ((size_t)(dl + 3) * HID + (g * 128 + sr)) * HID + k0;
        const char* pb = (const char*)srcB + hf;
        lds_st16(Bl, sr, hf + 0,  *(const int4*)(pb));
        lds_st16(Bl, sr, hf + 16, *(const int4*)(pb + 16));
      }
      __syncthreads();
      f16x8 af[4], bf[4];
#pragma unroll
      for (int m = 0; m < 4; ++m) {
        int lr = wr + m * 16 + ln;
        int tt = (lr & 31) + dl;
        tt = (tt < 0) ? -tt : ((tt > 31) ? 62 - tt : tt);   // reflect padding
        af[m] = lds_ld_frag(Al, (lr & ~31) | tt, q);
      }
#pragma unroll
      for (int n = 0; n < 4; ++n) bf[n] = lds_ld_frag(Bl, wc + n * 16 + ln, q);
#pragma unroll
      for (int m = 0; m < 4; ++m)
#pragma unroll
        for (int n = 0; n < 4; ++n)
          acc[m][n] = __builtin_amdgcn_mfma_f32_16x16x32_f16(af[m], bf[n], acc[m][n], 0, 0, 0);
    }
  }
  const float pa = *prelu_a;
  const float* bg = (g == 0) ? b1 : (g == 1) ? b3 : (g == 2) ? b5 : b7;
#pragma unroll
  for (int m = 0; m < 4; ++m)
#pragma unroll
    for (int i = 0; i < 4; ++i) {
      const int R = r0 + wr + m * 16 + q * 4 + i;
#pragma unroll
      for (int n = 0; n < 4; ++n) {
        const int cg = wc + n * 16 + ln;             // 0..127 within group
        float v = acc[m][n][i] + bg[cg];
        v = (v >= 0.f) ? v : pa * v;
        y[(size_t)R * HID + g * 128 + cg] = (f16)v;
      }
    }
}

// ---------------- out GEMM: comm_pred = y @ Wout + bout (f16 MFMA, N=64) ----------------
__global__ __launch_bounds__(256) void out_mfma_kernel(
    const f16* __restrict__ y, const f16* __restrict__ Wout_t,
    const float* __restrict__ bout, float* __restrict__ out)
{
  __shared__ __align__(16) char lds[12288];
  char* Al = lds;             // 128 x 64B
  char* Bl = lds + 8192;      // 64 x 64B
  const int tid = threadIdx.x;
  const int r0 = blockIdx.x * 128;
  const int sr = tid >> 1, hf = (tid & 1) * 32;
  const int wave = tid >> 6, lane = tid & 63;
  const int q = lane >> 4, ln = lane & 15;

  f32x4 acc[2][4] = {};
  const f16* srcA = y + (size_t)(r0 + sr) * HID;
  const f16* srcB = Wout_t + (size_t)(tid >> 2) * HID;  // 4 threads per row
  const int bo = (tid & 3) * 16;

  for (int k0 = 0; k0 < HID; k0 += 32) {
    __syncthreads();
    {
      const char* pa = (const char*)(srcA + k0) + hf;
      lds_st16(Al, sr, hf + 0,  *(const int4*)(pa));
      lds_st16(Al, sr, hf + 16, *(const int4*)(pa + 16));
      const char* pb = (const char*)(srcB + k0) + bo;
      lds_st16(Bl, tid >> 2, bo, *(const int4*)(pb));
    }
    __syncthreads();
    f16x8 af[2], bf[4];
#pragma unroll
    for (int m = 0; m < 2; ++m) af[m] = lds_ld_frag(Al, wave * 32 + m * 16 + ln, q);
#pragma unroll
    for (int n = 0; n < 4; ++n) bf[n] = lds_ld_frag(Bl, n * 16 + ln, q);
#pragma unroll
    for (int m = 0; m < 2; ++m)
#pragma unroll
      for (int n = 0; n < 4; ++n)
        acc[m][n] = __builtin_amdgcn_mfma_f32_16x16x32_f16(af[m], bf[n], acc[m][n], 0, 0, 0);
  }
#pragma unroll
  for (int m = 0; m < 2; ++m)
#pragma unroll
    for (int i = 0; i < 4; ++i) {
      const int R = r0 + wave * 32 + m * 16 + q * 4 + i;
#pragma unroll
      for (int n = 0; n < 4; ++n) {
        const int C = n * 16 + ln;
        out[(size_t)R * CCH + C] = acc[m][n][i] + bout[C];
      }
    }
}

// ---------------- end-token mask, in place on d_out ----------------
__global__ void mask_kernel(float* __restrict__ out) {
  const int row  = blockIdx.x;     // 0..2047 (e,s)
  const int lane = threadIdx.x;    // 0..63 = channel
  float* base = out + (long)row * (LSEQ * CCH);
  int ended = 0;
  for (int l = 0; l < LSEQ; ++l) {
    float v = base[l * CCH + lane];
    float mv = v; int mi = lane;
#pragma unroll
    for (int off = 32; off > 0; off >>= 1) {
      float ov = __shfl_xor(mv, off);
      int   oi = __shfl_xor(mi, off);
      if (ov > mv || (ov == mv && oi < mi)) { mv = ov; mi = oi; }
    }
    if (ended) base[l * CCH + lane] = 0.f;
    ended |= (mi == 0);
  }
}

extern "C" void kernel_launch(void* const* d_in, const int* in_sizes, int n_in,
                              void* d_out, int out_size, void* d_ws, size_t ws_size,
                              hipStream_t stream) {
  const float* x    = (const float*)d_in[0];
  const float* Wx   = (const float*)d_in[1];
  const float* bx   = (const float*)d_in[2];
  const float* Wh   = (const float*)d_in[3];
  const float* bh   = (const float*)d_in[4];
  const float* pa   = (const float*)d_in[5];
  const float* Wout = (const float*)d_in[6];
  const float* bout = (const float*)d_in[7];
  const float* cw1  = (const float*)d_in[8];
  const float* cb1  = (const float*)d_in[9];
  const float* cw3  = (const float*)d_in[10];
  const float* cb3  = (const float*)d_in[11];
  const float* cw5  = (const float*)d_in[12];
  const float* cb5  = (const float*)d_in[13];
  const float* cw7  = (const float*)d_in[14];
  const float* cb7  = (const float*)d_in[15];
  float* out = (float*)d_out;

  // workspace layout (~140 MB, fits proven ws >= 143.6 MB)
  char* p = (char*)d_ws;
  f16*   hs_hi  = (f16*)p;   p += (size_t)NROW * LSEQ * HID * 2;   // 64 MB
  f16*   y      = (f16*)p;   p += (size_t)NL * HID * 2;            // 64 MB
  float* xw     = (float*)p; p += (size_t)NROW * HID * 4;          // 4 MB
  f16*   hlo0   = (f16*)p;   p += (size_t)NROW * HID * 2;          // 2 MB
  f16*   hlo1   = (f16*)p;   p += (size_t)NROW * HID * 2;          // 2 MB
  f16*   Wc_t   = (f16*)p;   p += (size_t)7 * 512 * 512 * 2;       // 3.5 MB
  f16*   Wh_t   = (f16*)p;   p += (size_t)512 * 512 * 2;           // 0.5 MB
  f16*   Wout_t = (f16*)p;   p += (size_t)64 * 512 * 2;

  pack_wc_kernel<<<7 * 512 * 512 / 256, 256, 0, stream>>>(cw1, cw3, cw5, cw7, Wc_t);
  pack_misc_kernel<<<(512 * 512 + 64 * 512) / 256, 256, 0, stream>>>(Wh, Wout, Wh_t, Wout_t);

  // xw = x @ Wx + bx (fp32)
  gemm64_kernel<<<dim3(NROW / 64, HID / 64), 256, 0, stream>>>(
      x, DIN, Wx, HID, xw, HID, DIN, nullptr, 0, bx);

  step0_kernel<<<NROW * HID / 256, 256, 0, stream>>>(xw, bh, hs_hi, hlo0);

  for (int t = 1; t < LSEQ; ++t) {
    f16* prev = (t & 1) ? hlo0 : hlo1;
    f16* cur  = (t & 1) ? hlo1 : hlo0;
    rnn_step_kernel<<<dim3(NROW / 128, HID / 128), 256, 0, stream>>>(
        hs_hi, prev, cur, Wh_t, xw, bh, t);
  }

  conv_mfma_kernel<<<dim3(NL / 128, 4), 256, 0, stream>>>(
      hs_hi, Wc_t, cb1, cb3, cb5, cb7, pa, y);

  out_mfma_kernel<<<NL / 128, 256, 0, stream>>>(y, Wout_t, bout, out);

  mask_kernel<<<NROW, 64, 0, stream>>>(out);
}

// Round 4
// 533.386 us; speedup vs baseline: 6.5367x; 1.8777x over previous
//
#include <hip/hip_runtime.h>
#include <cmath>

#define LSEQ 32
#define HID  512
#define DIN  1536
#define CCH  64
#define NROW 2048          // E*S
#define NL   65536         // NROW*LSEQ

typedef _Float16 f16;
typedef _Float16 f16x8 __attribute__((ext_vector_type(8)));
typedef float    f32x4 __attribute__((ext_vector_type(4)));

__device__ __forceinline__ float fast_tanh(float x) {
  float e = __expf(2.0f * x);
  return 1.0f - 2.0f * __builtin_amdgcn_rcpf(e + 1.0f);
}

// 64B-row LDS tile, 16B-granularity XOR swizzle: bank bits[6:4] = (r&1, chunk^( (r>>1)&3 ))
__device__ __forceinline__ int offA(int r, int b) {
  return (r << 6) + (b ^ (((r >> 1) & 3) << 4));
}
// 1KB-row LDS tile: bank bits[6:4] = chunk^(r&7)
__device__ __forceinline__ int offB(int r, int b) {
  return (r << 10) + (b ^ ((r & 7) << 4));
}

// ---------------- pack conv weights transposed: Wc_t[dl+3][c][k] f16 ----------------
__global__ void pack_wc_kernel(const float* __restrict__ w1, const float* __restrict__ w3,
                               const float* __restrict__ w5, const float* __restrict__ w7,
                               f16* __restrict__ Wc_t) {
  int idx = blockIdx.x * 256 + threadIdx.x;
  if (idx >= 7 * 512 * 512) return;
  int k   = idx & 511;
  int c   = (idx >> 9) & 511;
  int dli = idx >> 18;
  int dl  = dli - 3;
  int g   = c >> 7, cg = c & 127;
  int K   = 2 * g + 1;
  int kk  = dl + g;
  float v = 0.f;
  if (kk >= 0 && kk < K) {
    const float* w = (g == 0) ? w1 : (g == 1) ? w3 : (g == 2) ? w5 : w7;
    v = w[(cg * 512 + k) * K + kk];
  }
  Wc_t[idx] = (f16)v;
}

// ---------------- pack Wh^T and Wout^T as f16 ----------------
__global__ void pack_misc_kernel(const float* __restrict__ Wh, const float* __restrict__ Wout,
                                 f16* __restrict__ Wh_t, f16* __restrict__ Wout_t) {
  int idx = blockIdx.x * 256 + threadIdx.x;
  if (idx < 512 * 512) {
    int n = idx >> 9, k = idx & 511;
    Wh_t[idx] = (f16)Wh[k * 512 + n];
  } else {
    int j = idx - 512 * 512;
    if (j < 64 * 512) {
      int c = j >> 9, k = j & 511;
      Wout_t[j] = (f16)Wout[k * 64 + c];
    }
  }
}

// ---------------- fp32 GEMM for xw = x @ Wx + bx ----------------
__global__ __launch_bounds__(256) void gemm64_kernel(
    const float* __restrict__ A, int lda,
    const float* __restrict__ B, int ldb,
    float* __restrict__ C, int ldc, int K,
    const float* __restrict__ bias)
{
  __shared__ float As[16][68];
  __shared__ float Bs[16][64];
  const int tid = threadIdx.x;
  const int m0 = blockIdx.x * 64;
  const int n0 = blockIdx.y * 64;
  const int ty = tid >> 4, tx = tid & 15;
  const int arow = tid >> 2;
  const int akq  = (tid & 3) * 4;
  const int brow = tid >> 4;
  const int bcol = (tid & 15) * 4;
  const float* Ap = A + (long)(m0 + arow) * lda + akq;
  const float* Bp = B + (long)brow * ldb + n0 + bcol;

  float acc[4][4] = {};
  for (int k0 = 0; k0 < K; k0 += 16) {
    float4 av = *(const float4*)(Ap + k0);
    float4 bv = *(const float4*)(Bp + (long)k0 * ldb);
    __syncthreads();
    As[akq + 0][arow] = av.x;
    As[akq + 1][arow] = av.y;
    As[akq + 2][arow] = av.z;
    As[akq + 3][arow] = av.w;
    *(float4*)&Bs[brow][bcol] = bv;
    __syncthreads();
#pragma unroll
    for (int k = 0; k < 16; ++k) {
      float4 a4 = *(const float4*)&As[k][ty * 4];
      float4 b4 = *(const float4*)&Bs[k][tx * 4];
      const float a[4] = {a4.x, a4.y, a4.z, a4.w};
      const float b[4] = {b4.x, b4.y, b4.z, b4.w};
#pragma unroll
      for (int i = 0; i < 4; ++i)
#pragma unroll
        for (int j = 0; j < 4; ++j)
          acc[i][j] = fmaf(a[i], b[j], acc[i][j]);
    }
  }
  const int cm = m0 + ty * 4;
  const int cn = n0 + tx * 4;
  float4 bv4 = *(const float4*)&bias[cn];
  const float bb[4] = {bv4.x, bv4.y, bv4.z, bv4.w};
#pragma unroll
  for (int i = 0; i < 4; ++i) {
    float4 o;
    o.x = acc[i][0] + bb[0]; o.y = acc[i][1] + bb[1];
    o.z = acc[i][2] + bb[2]; o.w = acc[i][3] + bb[3];
    *(float4*)(C + (long)(cm + i) * ldc + cn) = o;
  }
}

// ---------------- step 0: h1 = tanh(xw + bh), write hi/lo f16 ----------------
__global__ void step0_kernel(const float* __restrict__ xw, const float* __restrict__ bh,
                             f16* __restrict__ hs_hi, f16* __restrict__ hlo0) {
  int idx = blockIdx.x * 256 + threadIdx.x;
  int n = idx >> 9, h = idx & 511;
  float v = fast_tanh(xw[idx] + bh[h]);
  f16 hi = (f16)v;
  hs_hi[(size_t)n * (LSEQ * HID) + h] = hi;
  hlo0[idx] = (f16)(v - (float)hi);
}

// ---------------- RNN step t: 64x64 tile, Wh-resident LDS, A hi/lo dbuf ----------------
__global__ __launch_bounds__(256) void rnn_step_kernel(
    f16* __restrict__ hs_hi, const f16* __restrict__ hlo_prev,
    f16* __restrict__ hlo_cur, const f16* __restrict__ Wh_t,
    const float* __restrict__ xw, const float* __restrict__ bh, int t)
{
  __shared__ __align__(16) char Bl[65536];      // 64 x 1KB (Wh_t cols, all K)
  __shared__ __align__(16) char Ah[2][4096];    // 64 x 64B
  __shared__ __align__(16) char Al[2][4096];
  const int tid = threadIdx.x, lane = tid & 63, wave = tid >> 6;
  const int r0 = blockIdx.x * 64, c0 = blockIdx.y * 64;

  {  // stage whole B slice (64KB)
    const int rr = tid >> 2;
    const char* src = (const char*)(Wh_t + (size_t)(c0 + rr) * HID);
#pragma unroll
    for (int i = 0; i < 16; ++i) {
      const int cb = (((tid & 3) + (i << 2)) << 4);
      *(int4*)(Bl + offB(rr, cb)) = *(const int4*)(src + cb);
    }
  }
  const int srw = tid >> 2, sb = (tid & 3) << 4;
  const char* srcH = (const char*)(hs_hi + ((size_t)(r0 + srw) * LSEQ + (t - 1)) * HID) + sb;
  const char* srcL = (const char*)(hlo_prev + (size_t)(r0 + srw) * HID) + sb;
  const int wofs = offA(srw, sb);
  *(int4*)(Ah[0] + wofs) = *(const int4*)(srcH);
  *(int4*)(Al[0] + wofs) = *(const int4*)(srcL);
  __syncthreads();

  const int wr = (wave >> 1) * 32, wc = (wave & 1) * 32;
  const int q = lane >> 4, ln = lane & 15;
  f32x4 acc[2][2] = {};

#pragma unroll
  for (int ks = 0; ks < 16; ++ks) {
    const int buf = ks & 1;
    int4 nh, nl;
    if (ks < 15) {                        // issue next-tile loads early
      nh = *(const int4*)(srcH + (ks + 1) * 64);
      nl = *(const int4*)(srcL + (ks + 1) * 64);
    }
    f16x8 ah[2], al[2], bf[2];
#pragma unroll
    for (int m = 0; m < 2; ++m) {
      const int r = wr + m * 16 + ln;
      ah[m] = *(const f16x8*)(Ah[buf] + offA(r, q << 4));
      al[m] = *(const f16x8*)(Al[buf] + offA(r, q << 4));
    }
#pragma unroll
    for (int n = 0; n < 2; ++n) {
      const int r = wc + n * 16 + ln;
      bf[n] = *(const f16x8*)(Bl + offB(r, (ks << 6) + (q << 4)));
    }
    __builtin_amdgcn_s_setprio(1);
#pragma unroll
    for (int m = 0; m < 2; ++m)
#pragma unroll
      for (int n = 0; n < 2; ++n) {
        acc[m][n] = __builtin_amdgcn_mfma_f32_16x16x32_f16(ah[m], bf[n], acc[m][n], 0, 0, 0);
        acc[m][n] = __builtin_amdgcn_mfma_f32_16x16x32_f16(al[m], bf[n], acc[m][n], 0, 0, 0);
      }
    __builtin_amdgcn_s_setprio(0);
    if (ks < 15) {                        // write-late, one barrier per k-step
      *(int4*)(Ah[buf ^ 1] + wofs) = nh;
      *(int4*)(Al[buf ^ 1] + wofs) = nl;
      __syncthreads();
    }
  }

#pragma unroll
  for (int m = 0; m < 2; ++m)
#pragma unroll
    for (int i = 0; i < 4; ++i) {
      const int R = r0 + wr + m * 16 + q * 4 + i;
#pragma unroll
      for (int n = 0; n < 2; ++n) {
        const int C = c0 + wc + n * 16 + ln;
        float v = fast_tanh(acc[m][n][i] + xw[(size_t)R * HID + C] + bh[C]);
        f16 hi = (f16)v;
        hs_hi[((size_t)R * LSEQ + t) * HID + C] = hi;
        hlo_cur[(size_t)R * HID + C] = (f16)(v - (float)hi);
      }
    }
}

// ---------------- fused Ted_Conv1d via MFMA: dbuf A+B, 1 barrier/phase ----------------
__global__ __launch_bounds__(256) void conv_mfma_kernel(
    const f16* __restrict__ hs_hi, const f16* __restrict__ Wc_t,
    const float* __restrict__ b1, const float* __restrict__ b3,
    const float* __restrict__ b5, const float* __restrict__ b7,
    const float* __restrict__ prelu_a, f16* __restrict__ y)
{
  __shared__ __align__(16) char Atile[2][8192];   // 128 x 64B
  __shared__ __align__(16) char Btile[2][8192];   // 128 x 64B
  const int tid = threadIdx.x, lane = tid & 63, wave = tid >> 6;
  const int r0 = blockIdx.x * 128, g = blockIdx.y, taps = 2 * g + 1;
  const int wr = (wave >> 1) * 64, wc = (wave & 1) * 64;
  const int q = lane >> 4, ln = lane & 15;

  const int srow = tid >> 1;
  const int sb   = (tid & 1) << 5;
  const char* srcA = (const char*)(hs_hi + (size_t)(r0 + srow) * HID) + sb;
  const int wA0 = offA(srow, sb), wA1 = offA(srow, sb + 16);

  // prologue: stage A(kk=0), B(kk=0, tap=0)
  *(int4*)(Atile[0] + wA0) = *(const int4*)(srcA);
  *(int4*)(Atile[0] + wA1) = *(const int4*)(srcA + 16);
  {
    const char* p = (const char*)(Wc_t + ((size_t)(0 - g + 3) * HID + (g * 128 + srow)) * HID) + sb;
    *(int4*)(Btile[0] + wA0) = *(const int4*)(p);
    *(int4*)(Btile[0] + wA1) = *(const int4*)(p + 16);
  }
  __syncthreads();

  f32x4 acc[4][4] = {};
  int cur = 0, curA = 0;
  for (int kk = 0; kk < 16; ++kk) {
    for (int tp = 0; tp < taps; ++tp) {
      const bool lastPhase = (kk == 15) && (tp == taps - 1);
      const int nkk = (tp == taps - 1) ? kk + 1 : kk;
      const int ntp = (tp == taps - 1) ? 0 : tp + 1;
      int4 rb0, rb1, ra0, ra1;
      bool stA = false;
      if (!lastPhase) {                    // issue next-phase global loads early
        const char* p = (const char*)(Wc_t + ((size_t)(ntp - g + 3) * HID + (g * 128 + srow)) * HID + nkk * 32) + sb;
        rb0 = *(const int4*)(p);
        rb1 = *(const int4*)(p + 16);
        if (ntp == 0) {
          stA = true;
          ra0 = *(const int4*)(srcA + nkk * 64);
          ra1 = *(const int4*)(srcA + nkk * 64 + 16);
        }
      }
      const int dl = tp - g;
      f16x8 af[4], bf[4];
#pragma unroll
      for (int m = 0; m < 4; ++m) {
        const int lr = wr + m * 16 + ln;
        int tt = (lr & 31) + dl;
        tt = (tt < 0) ? -tt : ((tt > 31) ? 62 - tt : tt);   // reflect
        af[m] = *(const f16x8*)(Atile[curA] + offA((lr & ~31) | tt, q << 4));
      }
#pragma unroll
      for (int n = 0; n < 4; ++n)
        bf[n] = *(const f16x8*)(Btile[cur] + offA(wc + n * 16 + ln, q << 4));
      __builtin_amdgcn_s_setprio(1);
#pragma unroll
      for (int m = 0; m < 4; ++m)
#pragma unroll
        for (int n = 0; n < 4; ++n)
          acc[m][n] = __builtin_amdgcn_mfma_f32_16x16x32_f16(af[m], bf[n], acc[m][n], 0, 0, 0);
      __builtin_amdgcn_s_setprio(0);
      if (!lastPhase) {                    // write-late + single barrier
        *(int4*)(Btile[cur ^ 1] + wA0) = rb0;
        *(int4*)(Btile[cur ^ 1] + wA1) = rb1;
        if (stA) {
          *(int4*)(Atile[curA ^ 1] + wA0) = ra0;
          *(int4*)(Atile[curA ^ 1] + wA1) = ra1;
        }
        __syncthreads();
        cur ^= 1;
        if (stA) curA ^= 1;
      }
    }
  }

  const float pa = *prelu_a;
  const float* bg = (g == 0) ? b1 : (g == 1) ? b3 : (g == 2) ? b5 : b7;
#pragma unroll
  for (int m = 0; m < 4; ++m)
#pragma unroll
    for (int i = 0; i < 4; ++i) {
      const int R = r0 + wr + m * 16 + q * 4 + i;
#pragma unroll
      for (int n = 0; n < 4; ++n) {
        const int cg = wc + n * 16 + ln;
        float v = acc[m][n][i] + bg[cg];
        v = (v >= 0.f) ? v : pa * v;
        y[(size_t)R * HID + g * 128 + cg] = (f16)v;
      }
    }
}

// ---------------- out GEMM: comm_pred = y @ Wout + bout ----------------
__global__ __launch_bounds__(256) void out_mfma_kernel(
    const f16* __restrict__ y, const f16* __restrict__ Wout_t,
    const float* __restrict__ bout, float* __restrict__ out)
{
  __shared__ __align__(16) char Bl[65536];        // 64 x 1KB (Wout_t, all K)
  __shared__ __align__(16) char Atile[2][8192];   // 128 x 64B
  const int tid = threadIdx.x, lane = tid & 63, wave = tid >> 6;
  const int r0 = blockIdx.x * 128;
  const int q = lane >> 4, ln = lane & 15;

  {
    const int rr = tid >> 2;
    const char* src = (const char*)(Wout_t + (size_t)rr * HID);
#pragma unroll
    for (int i = 0; i < 16; ++i) {
      const int cb = (((tid & 3) + (i << 2)) << 4);
      *(int4*)(Bl + offB(rr, cb)) = *(const int4*)(src + cb);
    }
  }
  const int srow = tid >> 1, sb = (tid & 1) << 5;
  const char* srcA = (const char*)(y + (size_t)(r0 + srow) * HID) + sb;
  const int wA0 = offA(srow, sb), wA1 = offA(srow, sb + 16);
  *(int4*)(Atile[0] + wA0) = *(const int4*)(srcA);
  *(int4*)(Atile[0] + wA1) = *(const int4*)(srcA + 16);
  __syncthreads();

  f32x4 acc[2][4] = {};
#pragma unroll
  for (int ks = 0; ks < 16; ++ks) {
    const int buf = ks & 1;
    int4 na0, na1;
    if (ks < 15) {
      na0 = *(const int4*)(srcA + (ks + 1) * 64);
      na1 = *(const int4*)(srcA + (ks + 1) * 64 + 16);
    }
    f16x8 af[2], bf[4];
#pragma unroll
    for (int m = 0; m < 2; ++m)
      af[m] = *(const f16x8*)(Atile[buf] + offA(wave * 32 + m * 16 + ln, q << 4));
#pragma unroll
    for (int n = 0; n < 4; ++n)
      bf[n] = *(const f16x8*)(Bl + offB(n * 16 + ln, (ks << 6) + (q << 4)));
#pragma unroll
    for (int m = 0; m < 2; ++m)
#pragma unroll
      for (int n = 0; n < 4; ++n)
        acc[m][n] = __builtin_amdgcn_mfma_f32_16x16x32_f16(af[m], bf[n], acc[m][n], 0, 0, 0);
    if (ks < 15) {
      *(int4*)(Atile[buf ^ 1] + wA0) = na0;
      *(int4*)(Atile[buf ^ 1] + wA1) = na1;
      __syncthreads();
    }
  }
#pragma unroll
  for (int m = 0; m < 2; ++m)
#pragma unroll
    for (int i = 0; i < 4; ++i) {
      const int R = r0 + wave * 32 + m * 16 + q * 4 + i;
#pragma unroll
      for (int n = 0; n < 4; ++n) {
        const int C = n * 16 + ln;
        out[(size_t)R * CCH + C] = acc[m][n][i] + bout[C];
      }
    }
}

// ---------------- end-token mask, in place on d_out ----------------
__global__ void mask_kernel(float* __restrict__ out) {
  const int row  = blockIdx.x;
  const int lane = threadIdx.x;
  float* base = out + (long)row * (LSEQ * CCH);
  int ended = 0;
  for (int l = 0; l < LSEQ; ++l) {
    float v = base[l * CCH + lane];
    float mv = v; int mi = lane;
#pragma unroll
    for (int off = 32; off > 0; off >>= 1) {
      float ov = __shfl_xor(mv, off);
      int   oi = __shfl_xor(mi, off);
      if (ov > mv || (ov == mv && oi < mi)) { mv = ov; mi = oi; }
    }
    if (ended) base[l * CCH + lane] = 0.f;
    ended |= (mi == 0);
  }
}

extern "C" void kernel_launch(void* const* d_in, const int* in_sizes, int n_in,
                              void* d_out, int out_size, void* d_ws, size_t ws_size,
                              hipStream_t stream) {
  const float* x    = (const float*)d_in[0];
  const float* Wx   = (const float*)d_in[1];
  const float* bx   = (const float*)d_in[2];
  const float* Wh   = (const float*)d_in[3];
  const float* bh   = (const float*)d_in[4];
  const float* pa   = (const float*)d_in[5];
  const float* Wout = (const float*)d_in[6];
  const float* bout = (const float*)d_in[7];
  const float* cw1  = (const float*)d_in[8];
  const float* cb1  = (const float*)d_in[9];
  const float* cw3  = (const float*)d_in[10];
  const float* cb3  = (const float*)d_in[11];
  const float* cw5  = (const float*)d_in[12];
  const float* cb5  = (const float*)d_in[13];
  const float* cw7  = (const float*)d_in[14];
  const float* cb7  = (const float*)d_in[15];
  float* out = (float*)d_out;

  char* p = (char*)d_ws;
  f16*   hs_hi  = (f16*)p;   p += (size_t)NROW * LSEQ * HID * 2;   // 64 MB
  f16*   y      = (f16*)p;   p += (size_t)NL * HID * 2;            // 64 MB
  float* xw     = (float*)p; p += (size_t)NROW * HID * 4;          // 4 MB
  f16*   hlo0   = (f16*)p;   p += (size_t)NROW * HID * 2;          // 2 MB
  f16*   hlo1   = (f16*)p;   p += (size_t)NROW * HID * 2;          // 2 MB
  f16*   Wc_t   = (f16*)p;   p += (size_t)7 * 512 * 512 * 2;       // 3.5 MB
  f16*   Wh_t   = (f16*)p;   p += (size_t)512 * 512 * 2;           // 0.5 MB
  f16*   Wout_t = (f16*)p;   p += (size_t)64 * 512 * 2;

  pack_wc_kernel<<<7 * 512 * 512 / 256, 256, 0, stream>>>(cw1, cw3, cw5, cw7, Wc_t);
  pack_misc_kernel<<<(512 * 512 + 64 * 512) / 256, 256, 0, stream>>>(Wh, Wout, Wh_t, Wout_t);

  gemm64_kernel<<<dim3(NROW / 64, HID / 64), 256, 0, stream>>>(
      x, DIN, Wx, HID, xw, HID, DIN, bx);

  step0_kernel<<<NROW * HID / 256, 256, 0, stream>>>(xw, bh, hs_hi, hlo0);

  for (int t = 1; t < LSEQ; ++t) {
    f16* prev = (t & 1) ? hlo0 : hlo1;
    f16* cur  = (t & 1) ? hlo1 : hlo0;
    rnn_step_kernel<<<dim3(NROW / 64, HID / 64), 256, 0, stream>>>(
        hs_hi, prev, cur, Wh_t, xw, bh, t);
  }

  conv_mfma_kernel<<<dim3(NL / 128, 4), 256, 0, stream>>>(
      hs_hi, Wc_t, cb1, cb3, cb5, cb7, pa, y);

  out_mfma_kernel<<<NL / 128, 256, 0, stream>>>(y, Wout_t, bout, out);

  mask_kernel<<<NROW, 64, 0, stream>>>(out);
}